// Round 1
// baseline (252.432 us; speedup 1.0000x reference)
//
#include <hip/hip_runtime.h>

// out = relu(w[0]*t1 + w[1]*t2 + b[0])  -- elementwise over 25,690,112 fp32.
// Memory-bound: float4 vector loads/stores, grid-stride, 2048-block cap.

__global__ void __launch_bounds__(256) fused_merge_relu_f4(
    const float4* __restrict__ t1,
    const float4* __restrict__ t2,
    float4* __restrict__ out,
    const float* __restrict__ w,
    const float* __restrict__ b,
    int n4)
{
    const float w0 = w[0];
    const float w1 = w[1];
    const float bb = b[0];

    int stride = gridDim.x * blockDim.x;
    for (int i = blockIdx.x * blockDim.x + threadIdx.x; i < n4; i += stride) {
        float4 a = t1[i];
        float4 c = t2[i];
        float4 r;
        r.x = fmaxf(fmaf(w0, a.x, fmaf(w1, c.x, bb)), 0.0f);
        r.y = fmaxf(fmaf(w0, a.y, fmaf(w1, c.y, bb)), 0.0f);
        r.z = fmaxf(fmaf(w0, a.z, fmaf(w1, c.z, bb)), 0.0f);
        r.w = fmaxf(fmaf(w0, a.w, fmaf(w1, c.w, bb)), 0.0f);
        out[i] = r;
    }
}

__global__ void __launch_bounds__(256) fused_merge_relu_tail(
    const float* __restrict__ t1,
    const float* __restrict__ t2,
    float* __restrict__ out,
    const float* __restrict__ w,
    const float* __restrict__ b,
    int start, int n)
{
    int i = start + blockIdx.x * blockDim.x + threadIdx.x;
    if (i < n) {
        out[i] = fmaxf(fmaf(w[0], t1[i], fmaf(w[1], t2[i], b[0])), 0.0f);
    }
}

extern "C" void kernel_launch(void* const* d_in, const int* in_sizes, int n_in,
                              void* d_out, int out_size, void* d_ws, size_t ws_size,
                              hipStream_t stream) {
    const float* t1 = (const float*)d_in[0];
    const float* t2 = (const float*)d_in[1];
    const float* w  = (const float*)d_in[2];
    const float* b  = (const float*)d_in[3];
    float* out = (float*)d_out;

    const int n  = out_size;          // 25,690,112
    const int n4 = n / 4;             // 6,422,528 float4 elements
    const int tail = n - n4 * 4;      // 0 for this shape

    const int block = 256;
    int grid = (n4 + block - 1) / block;
    if (grid > 2048) grid = 2048;     // 256 CU x 8 blocks/CU, grid-stride covers rest

    fused_merge_relu_f4<<<grid, block, 0, stream>>>(
        (const float4*)t1, (const float4*)t2, (float4*)out, w, b, n4);

    if (tail > 0) {
        int tg = (tail + block - 1) / block;
        fused_merge_relu_tail<<<tg, block, 0, stream>>>(t1, t2, out, w, b, n4 * 4, n);
    }
}